// Round 1
// baseline (552.189 us; speedup 1.0000x reference)
//
#include <hip/hip_runtime.h>
#include <hip/hip_bf16.h>

typedef __bf16 bfv8 __attribute__((ext_vector_type(8)));
typedef float f32x4 __attribute__((ext_vector_type(4)));

constexpr int XW_LD = 392;   // 384 + 8 pad (bf16) -> 784B row stride, 16B aligned, 2-way-bank only
constexpr int QK_LD = 40;    // 32 + 8
constexpr int VT_LD = 72;    // 64 + 8
constexpr int P_LD  = 72;    // 64 + 8

// Convert weights to bf16, transposed: qT[col][k] = w_qkv[k][col], pT[col][k] = w_proj[k][col]
__global__ __launch_bounds__(256)
void prep_weights(const float* __restrict__ w_qkv, const float* __restrict__ w_proj,
                  unsigned short* __restrict__ qT, unsigned short* __restrict__ pT)
{
    int i = blockIdx.x * 256 + threadIdx.x;
    const int NQ = 1152 * 384;
    if (i < NQ) {
        int c = i / 384, k = i - c * 384;
        __bf16 h = (__bf16)w_qkv[k * 1152 + c];
        qT[i] = *(unsigned short*)&h;
    } else {
        int j = i - NQ;
        if (j < 384 * 384) {
            int c = j / 384, k = j - c * 384;
            __bf16 h = (__bf16)w_proj[k * 384 + c];
            pT[j] = *(unsigned short*)&h;
        }
    }
}

// One workgroup per 8x8 window. 512 threads = 8 waves.
// MFMA 16x16x32 bf16 layouts (learn_hip m89/m92-verified):
//   a_frag lane l elem j = A[l&15][(l>>4)*8 + j]          (bf16x8 contiguous-k load)
//   b_frag lane l elem j = B[(l>>4)*8 + j][l&15] = BT[l&15][(l>>4)*8+j]
//   d      lane l reg  r = D[(l>>4)*4 + r][l&15]
__global__ __launch_bounds__(512)
void win_attn(const float* __restrict__ x,
              const float* __restrict__ b_qkv,
              const float* __restrict__ b_proj,
              const unsigned short* __restrict__ qT_,
              const unsigned short* __restrict__ pT_,
              float* __restrict__ out)
{
    __shared__ __bf16 sX[64 * XW_LD];        // x window, bf16          (50176 B)
    __shared__ __bf16 sO[64 * XW_LD];        // attn output concat      (50176 B)
    __shared__ __bf16 sQ[2 * 64 * QK_LD];    // Q for 2 heads           (10240 B)
    __shared__ __bf16 sK[2 * 64 * QK_LD];    // K for 2 heads           (10240 B)
    __shared__ __bf16 sVT[2 * 32 * VT_LD];   // V transposed, 2 heads   ( 9216 B)
    __shared__ __bf16 sP[2 * 64 * P_LD];     // softmax probs, 2 heads  (18432 B)
    // total 148,480 B < 160 KiB

    const __bf16* wqkvT  = (const __bf16*)qT_;
    const __bf16* wprojT = (const __bf16*)pT_;

    const int wid  = blockIdx.x;
    const int bb   = wid >> 6;          // batch
    const int wy   = (wid >> 3) & 7;    // window row
    const int wx   = wid & 7;           // window col
    const int tid  = threadIdx.x;
    const int lane = tid & 63;
    const int wv   = tid >> 6;          // wave id 0..7
    const int lr   = lane & 15;
    const int lg   = lane >> 4;
    const int k8   = lg * 8;

    const size_t gbase = ((size_t)(bb * 64 + wy * 8) * 64 + wx * 8) * 384;

    // ---- stage x window -> sX as bf16 ----
    {
        const float* xb = x + gbase;
        for (int i = tid; i < 64 * 96; i += 512) {
            int t  = i / 96;
            int c4 = (i - t * 96) * 4;
            const float4 v = *(const float4*)(xb + (size_t)((t >> 3) * 64 + (t & 7)) * 384 + c4);
            __bf16* d = &sX[t * XW_LD + c4];
            d[0] = (__bf16)v.x; d[1] = (__bf16)v.y; d[2] = (__bf16)v.z; d[3] = (__bf16)v.w;
        }
    }
    __syncthreads();

    for (int hp = 0; hp < 6; ++hp) {    // head pairs (2*hp, 2*hp+1)
        // ---- QKV GEMM: 48 output tiles (12 ntiles x 4 mtiles), M=64 N=192 K=384 ----
        for (int pass = 0; pass < 2; ++pass) {
            const int n  = (pass == 0) ? wv : 8 + (wv & 3);
            const int m0 = (pass == 0) ? 0 : (wv >> 2) * 2;
            const int nm = (pass == 0) ? 4 : 2;
            const int t3  = n >> 2;          // 0=Q 1=K 2=V
            const int sub = n & 3;
            const int hl  = sub >> 1;        // head-local 0/1
            const int d0  = (sub & 1) * 16;  // dim tile base
            const int col = t3 * 384 + (hp * 2 + hl) * 32 + d0 + lr;  // global qkv col
            const __bf16* bp = wqkvT + (size_t)col * 384 + k8;
            f32x4 acc[4];
            for (int m = 0; m < 4; ++m) acc[m] = {0.f, 0.f, 0.f, 0.f};
            for (int kk = 0; kk < 12; ++kk) {
                const bfv8 bf = *(const bfv8*)(bp + kk * 32);
                #pragma unroll
                for (int m = 0; m < 4; ++m) {
                    if (m < nm) {
                        const bfv8 af = *(const bfv8*)&sX[((m0 + m) * 16 + lr) * XW_LD + kk * 32 + k8];
                        acc[m] = __builtin_amdgcn_mfma_f32_16x16x32_bf16(af, bf, acc[m], 0, 0, 0);
                    }
                }
            }
            const float bias = b_qkv[col];
            for (int m = 0; m < nm; ++m) {
                const int mt = m0 + m;
                #pragma unroll
                for (int r = 0; r < 4; ++r) {
                    const int tokr = mt * 16 + lg * 4 + r;
                    const __bf16 bv = (__bf16)(acc[m][r] + bias);
                    if (t3 == 0)      sQ[(hl * 64 + tokr) * QK_LD + d0 + lr] = bv;
                    else if (t3 == 1) sK[(hl * 64 + tokr) * QK_LD + d0 + lr] = bv;
                    else              sVT[hl * 32 * VT_LD + (d0 + lr) * VT_LD + tokr] = bv;  // transposed
                }
            }
        }
        __syncthreads();

        // ---- attention: wave -> head hl = wv>>2, query strip ms = wv&3 (16 rows) ----
        {
            const int hl = wv >> 2;
            const int ms = wv & 3;
            const bfv8 qf = *(const bfv8*)&sQ[(hl * 64 + ms * 16 + lr) * QK_LD + k8];
            f32x4 s[4];
            #pragma unroll
            for (int n = 0; n < 4; ++n) {
                const bfv8 kf = *(const bfv8*)&sK[(hl * 64 + n * 16 + lr) * QK_LD + k8];
                f32x4 z = {0.f, 0.f, 0.f, 0.f};
                s[n] = __builtin_amdgcn_mfma_f32_16x16x32_bf16(qf, kf, z, 0, 0, 0);
            }
            const float SC = 0.17677669529663687f;  // 32^-0.5
            float rinv[4];
            #pragma unroll
            for (int r = 0; r < 4; ++r) {
                float mx = -1e30f;
                #pragma unroll
                for (int n = 0; n < 4; ++n) { s[n][r] *= SC; mx = fmaxf(mx, s[n][r]); }
                #pragma unroll
                for (int off = 1; off < 16; off <<= 1) mx = fmaxf(mx, __shfl_xor(mx, off, 64));
                float sum = 0.f;
                #pragma unroll
                for (int n = 0; n < 4; ++n) { const float p = __expf(s[n][r] - mx); s[n][r] = p; sum += p; }
                #pragma unroll
                for (int off = 1; off < 16; off <<= 1) sum += __shfl_xor(sum, off, 64);
                rinv[r] = 1.0f / sum;
            }
            // store P (layout conversion D-frag -> A-frag goes through LDS)
            #pragma unroll
            for (int n = 0; n < 4; ++n)
                #pragma unroll
                for (int r = 0; r < 4; ++r)
                    sP[(hl * 64 + ms * 16 + lg * 4 + r) * P_LD + n * 16 + lr] = (__bf16)s[n][r];
            __syncthreads();

            // ---- P @ V ----
            f32x4 o[2];
            o[0] = {0.f, 0.f, 0.f, 0.f}; o[1] = {0.f, 0.f, 0.f, 0.f};
            #pragma unroll
            for (int ks = 0; ks < 2; ++ks) {
                const bfv8 pf = *(const bfv8*)&sP[(hl * 64 + ms * 16 + lr) * P_LD + ks * 32 + k8];
                #pragma unroll
                for (int n = 0; n < 2; ++n) {
                    const bfv8 vf = *(const bfv8*)&sVT[hl * 32 * VT_LD + (n * 16 + lr) * VT_LD + ks * 32 + k8];
                    o[n] = __builtin_amdgcn_mfma_f32_16x16x32_bf16(pf, vf, o[n], 0, 0, 0);
                }
            }
            const int colbase = (hp * 2 + hl) * 32;
            #pragma unroll
            for (int n = 0; n < 2; ++n)
                #pragma unroll
                for (int r = 0; r < 4; ++r)
                    sO[(ms * 16 + lg * 4 + r) * XW_LD + colbase + n * 16 + lr] = (__bf16)(o[n][r] * rinv[r]);
        }
        __syncthreads();
    }

    // ---- projection: Out = sO(64x384) @ Wp(384x384) + b_proj ----
    float* ob = out + gbase;
    for (int nn = 0; nn < 3; ++nn) {
        const int n = wv + nn * 8;
        const int col = n * 16 + lr;
        const __bf16* bp = wprojT + (size_t)col * 384 + k8;
        f32x4 acc[4];
        for (int m = 0; m < 4; ++m) acc[m] = {0.f, 0.f, 0.f, 0.f};
        for (int kk = 0; kk < 12; ++kk) {
            const bfv8 bf = *(const bfv8*)(bp + kk * 32);
            #pragma unroll
            for (int m = 0; m < 4; ++m) {
                const bfv8 af = *(const bfv8*)&sO[(m * 16 + lr) * XW_LD + kk * 32 + k8];
                acc[m] = __builtin_amdgcn_mfma_f32_16x16x32_bf16(af, bf, acc[m], 0, 0, 0);
            }
        }
        const float bias = b_proj[col];
        #pragma unroll
        for (int m = 0; m < 4; ++m)
            #pragma unroll
            for (int r = 0; r < 4; ++r) {
                const int t = m * 16 + lg * 4 + r;
                ob[(size_t)((t >> 3) * 64 + (t & 7)) * 384 + col] = acc[m][r] + bias;
            }
    }
}

extern "C" void kernel_launch(void* const* d_in, const int* in_sizes, int n_in,
                              void* d_out, int out_size, void* d_ws, size_t ws_size,
                              hipStream_t stream)
{
    const float* x      = (const float*)d_in[0];
    const float* w_qkv  = (const float*)d_in[1];
    const float* b_qkv  = (const float*)d_in[2];
    const float* w_proj = (const float*)d_in[3];
    const float* b_proj = (const float*)d_in[4];
    float* out = (float*)d_out;

    unsigned short* qT = (unsigned short*)d_ws;          // 1152*384 bf16 = 884736 B
    unsigned short* pT = qT + 1152 * 384;                // 384*384 bf16  = 294912 B

    const int NPREP = 1152 * 384 + 384 * 384;
    prep_weights<<<(NPREP + 255) / 256, 256, 0, stream>>>(w_qkv, w_proj, qT, pT);
    win_attn<<<2048, 512, 0, stream>>>(x, b_qkv, b_proj, qT, pT, out);
}